// Round 18
// baseline (693.686 us; speedup 1.0000x reference)
//
#include <hip/hip_runtime.h>
#include <cstdint>
#include <cstddef>

#define SS 8192
#define DD 1024
#define DI2 2048
#define NR 16384   // B*S

#define LOG2_09 (-0.152003093445050f)   // log2(0.9)
#define LAMBDA16 0.185302018885184f     // 0.9^16

typedef __attribute__((ext_vector_type(4))) float f32x4;
typedef __attribute__((ext_vector_type(8))) __bf16 bf16x8;

union U16 { uint4 u; bf16x8 b; };

static __device__ __forceinline__ f32x4 MFMA(uint4 a, uint4 b, f32x4 c) {
  U16 ua, ub; ua.u = a; ub.u = b;
  return __builtin_amdgcn_mfma_f32_16x16x32_bf16(ua.b, ub.b, c, 0, 0, 0);
}

static __device__ __forceinline__ unsigned short f2bf(float f) {
  union { float f; unsigned u; } v; v.f = f;
  return (unsigned short)((v.u + 0x7FFFu + ((v.u >> 16) & 1u)) >> 16);
}
static __device__ __forceinline__ float bf2f(unsigned b) {
  union { unsigned u; float f; } v; v.u = b << 16; return v.f;
}
static __device__ __forceinline__ void unpack8(uint4 u, float* f) {
  f[0] = bf2f(u.x & 0xFFFFu); f[1] = bf2f(u.x >> 16);
  f[2] = bf2f(u.y & 0xFFFFu); f[3] = bf2f(u.y >> 16);
  f[4] = bf2f(u.z & 0xFFFFu); f[5] = bf2f(u.z >> 16);
  f[6] = bf2f(u.w & 0xFFFFu); f[7] = bf2f(u.w >> 16);
}

// async global->LDS, 16B per lane. LDS dest is wave-uniform base + lane*16.
static __device__ __forceinline__ void glds16(const unsigned short* g, char* l) {
  __builtin_amdgcn_global_load_lds(
      (const __attribute__((address_space(1))) unsigned int*)g,
      (__attribute__((address_space(3))) unsigned int*)l, 16, 0, 0);
}

// ---------------- weight transpose + cast: out[c][r] = bf16(in[r][c]) ----------------
__global__ __launch_bounds__(256)
void transpose_cast(const float* __restrict__ in, unsigned short* __restrict__ out, int R, int Cc) {
  __shared__ float tile[32][33];
  const int r0 = blockIdx.y * 32, c0 = blockIdx.x * 32;
  const int tx = threadIdx.x, ty = threadIdx.y;
#pragma unroll
  for (int i = 0; i < 4; i++)
    tile[ty + i * 8][tx] = in[(size_t)(r0 + ty + i * 8) * Cc + c0 + tx];
  __syncthreads();
#pragma unroll
  for (int i = 0; i < 4; i++)
    out[(size_t)(c0 + ty + i * 8) * R + r0 + tx] = f2bf(tile[tx][ty + i * 8]);
}

// ---------------- RMSNorm (fp32 in -> bf16 out) ----------------
__global__ __launch_bounds__(256)
void rmsnorm_kernel(const float* __restrict__ x, const float* __restrict__ w,
                    unsigned short* __restrict__ out) {
  const int row = blockIdx.x, t = threadIdx.x;
  const float4 v = ((const float4*)(x + (size_t)row * DD))[t];
  float ss = v.x * v.x + v.y * v.y + v.z * v.z + v.w * v.w;
  __shared__ float sred[256];
  sred[t] = ss;
  __syncthreads();
  for (int o = 128; o > 0; o >>= 1) {
    if (t < o) sred[t] += sred[t + o];
    __syncthreads();
  }
  const float rr = rsqrtf(sred[0] * (1.0f / (float)DD) + 1e-5f);
  const float4 wv = ((const float4*)w)[t];
  uint2 pk;
  pk.x = (unsigned)f2bf(v.x * rr * wv.x) | ((unsigned)f2bf(v.y * rr * wv.y) << 16);
  pk.y = (unsigned)f2bf(v.z * rr * wv.z) | ((unsigned)f2bf(v.w * rr * wv.w) << 16);
  *(uint2*)(out + (size_t)row * DD + t * 4) = pk;
}

// ---------------- 256x256-tile bf16 GEMM: C = A[M][.] @ Bt[N][.]^T ----------------
// 8 waves, wave grid 2Mx4N (128x64 out/wave). BK=64, DOUBLE-buffered LDS (2 x 64KB),
// ONE barrier per K-tile; stage(kt+1) issued at body top -> vmcnt(0) drain at body end
// is covered by the ~600cyc compute window (vs r12's failed BK=32 depth-1 ~300cyc).
// Barrier count halved vs BK=32 (r14 baseline, MfmaUtil 42%).
// XCD m-slice remap when mblocks%8==0. Modes identical to r14 (best measured 642.9us).
enum { EP_BF16 = 0, EP_F32_RES = 3, EP_STATE = 4, EP_SCORE = 6, EP_PVX = 7, EP_QKV = 8 };

template <int MODE>
__global__ __launch_bounds__(512, 2)
void gemm256(const unsigned short* __restrict__ A, const unsigned short* __restrict__ Bt,
             unsigned short* __restrict__ Cb, unsigned short* __restrict__ Ct,
             float* __restrict__ Cf, const float* __restrict__ resid,
             unsigned short* __restrict__ Cx,
             int M, int N, int kLen, int lda, int ldb, float scale) {
  __shared__ char sLds[131072];
  const int t = threadIdx.x, lane = t & 63, wid = t >> 6;
  const int wr = wid >> 2, wc = wid & 3;
  const int l15 = lane & 15, lh = lane >> 4;
  const int mblocks = M >> 8;
  int m0, n0;
  if constexpr (MODE == EP_SCORE) {
    const int p = (int)blockIdx.x;
    const int mt = (p >= 6) ? 3 : (p >= 3) ? 2 : (p >= 1) ? 1 : 0;
    const int nt = p - ((mt * (mt + 1)) >> 1);
    m0 = mt << 8; n0 = nt << 8;
  } else if ((mblocks & 7) == 0) {   // XCD m-slice remap
    const int msl = mblocks >> 3;
    const int xcd = (int)blockIdx.x & 7, loc = (int)blockIdx.x >> 3;
    m0 = (xcd * msl + (loc % msl)) << 8;
    n0 = (loc / msl) << 8;
  } else {
    m0 = ((int)blockIdx.x % mblocks) << 8;
    n0 = ((int)blockIdx.x / mblocks) << 8;
  }
  int zb = 0, zg = 0;
  const unsigned short* Abase = A;
  const unsigned short* Bbase = Bt;
  if constexpr (MODE == EP_STATE || MODE == EP_SCORE || MODE == EP_PVX) {
    const int gb = blockIdx.z;
    zb = gb >> 3; zg = gb & 7;
    if constexpr (MODE == EP_STATE) {
      Abase = A + (size_t)zb * DD * SS + (size_t)zg * 1024;
      Bbase = Bt + (size_t)zb * DD * SS + (size_t)zg * 1024;
    } else if constexpr (MODE == EP_SCORE) {
      Abase = A + ((size_t)zb * SS + (size_t)zg * 1024) * (size_t)lda;
      Bbase = Bt + ((size_t)zb * SS + (size_t)zg * 1024) * (size_t)ldb;
    } else {  // EP_PVX: A = sbuf[gb], B = vt superchunk
      Abase = A + ((size_t)blockIdx.z << 20);
      Bbase = Bt + (size_t)zb * DD * SS + (size_t)zg * 1024;
    }
  }
  // staging geometry: per 64-row span h, thread does row rr8 = wid*8+(lane>>3),
  // 16B at swizzled col (write-linear LDS, inverse-swizzled global source col).
  const int rr8 = wid * 8 + (lane >> 3);
  const int sc8 = (((lane & 7) ^ ((lane >> 3) & 7))) * 8;   // bf16 elems
  const unsigned short* pAr = Abase + (size_t)(m0 + rr8) * lda + sc8;
  const unsigned short* pBr = Bbase + (size_t)(n0 + rr8) * ldb + sc8;
  // EP_PVX second-section bases (qs rows / Minit rows) and band length (64-unit tiles)
  int ntV = 0;
  const unsigned short *pA2r = nullptr, *pB2r = nullptr;
  if constexpr (MODE == EP_PVX) {
    ntV = ((m0 >> 8) + 1) << 2;  // banded S@V: k <= (mt+1)*256
    const unsigned short* qsb = Cx + ((size_t)zb * SS + (size_t)zg * 1024) * DD;
    pA2r = qsb + (size_t)(m0 + rr8) * DD + sc8;
    const unsigned short* mnb = Ct + ((size_t)blockIdx.z << 20);
    pB2r = mnb + (size_t)(n0 + rr8) * 1024 + sc8;
  }
  // swizzled read offsets: row stride 128B; kk selects k-half (64B)
  int offA[8][2], offB[4][2];
#pragma unroll
  for (int mf = 0; mf < 8; mf++) {
    const int r = wr * 128 + mf * 16 + l15;
#pragma unroll
    for (int kk = 0; kk < 2; kk++)
      offA[mf][kk] = r * 128 + ((kk * 64 + lh * 16) ^ ((r & 7) << 4));
  }
#pragma unroll
  for (int nf = 0; nf < 4; nf++) {
    const int r = wc * 64 + nf * 16 + l15;
#pragma unroll
    for (int kk = 0; kk < 2; kk++)
      offB[nf][kk] = r * 128 + ((kk * 64 + lh * 16) ^ ((r & 7) << 4));
  }
  int NT = kLen >> 6;
  if constexpr (MODE == EP_PVX) NT = ntV + 16;  // band + Minit (K=1024)
#define BUFA(tt) (sLds + ((tt) & 1) * 65536)
#define BUFB(tt) (sLds + ((tt) & 1) * 65536 + 32768)
  auto stage = [&](int tt) {
    const unsigned short* a = pAr;
    const unsigned short* b = pBr;
    size_t la = lda, lb = ldb;
    int ke = tt * 64;
    if constexpr (MODE == EP_PVX) {
      if (tt >= ntV) { a = pA2r; b = pB2r; la = DD; lb = 1024; ke = (tt - ntV) * 64; }
    }
    char* BA = BUFA(tt) + wid * 1024;
    char* BB = BUFB(tt) + wid * 1024;
#pragma unroll
    for (int h = 0; h < 4; h++) {
      glds16(a + (size_t)(h * 64) * la + ke, BA + h * 8192);
      glds16(b + (size_t)(h * 64) * lb + ke, BB + h * 8192);
    }
  };
  stage(0);
  asm volatile("s_waitcnt vmcnt(0)" ::: "memory");
  __builtin_amdgcn_s_barrier();
  f32x4 acc[8][4] = {};
  for (int kt = 0; kt < NT; ++kt) {
    const char* At  = BUFA(kt);
    const char* Bt_ = BUFB(kt);
    // prefetch next tile into the other buffer (readers finished before last barrier)
    if (kt + 1 < NT) stage(kt + 1);
#pragma unroll
    for (int kk = 0; kk < 2; kk++) {
      uint4 av[8], bv[4];
#pragma unroll
      for (int i = 0; i < 8; i++) av[i] = *(const uint4*)(At + offA[i][kk]);
#pragma unroll
      for (int i = 0; i < 4; i++) bv[i] = *(const uint4*)(Bt_ + offB[i][kk]);
      __builtin_amdgcn_s_setprio(1);
#pragma unroll
      for (int mf = 0; mf < 8; mf++)
#pragma unroll
        for (int nf = 0; nf < 4; nf++)
          acc[mf][nf] = MFMA(av[mf], bv[nf], acc[mf][nf]);
      __builtin_amdgcn_s_setprio(0);
    }
    // drain own glds (issued a full body ago -> typically complete), then rendezvous
    asm volatile("s_waitcnt vmcnt(0)" ::: "memory");
    __builtin_amdgcn_s_barrier();
  }
#undef BUFA
#undef BUFB
#pragma unroll
  for (int mf = 0; mf < 8; mf++) {
    const int r0 = m0 + wr * 128 + mf * 16 + lh * 4;
#pragma unroll
    for (int nf = 0; nf < 4; nf++) {
      const int c = n0 + wc * 64 + nf * 16 + l15;
      f32x4 v = acc[mf][nf] * scale;
      if constexpr (MODE == EP_F32_RES) {
#pragma unroll
        for (int jj = 0; jj < 4; jj++) {
          const size_t idx = (size_t)(r0 + jj) * N + c;
          Cf[idx] = v[jj] + resid[idx];
        }
      } else if constexpr (MODE == EP_STATE) {
        unsigned short* Tg = Cb + ((size_t)blockIdx.z << 20);
#pragma unroll
        for (int jj = 0; jj < 4; jj++)
          Tg[(size_t)(r0 + jj) * 1024 + c] = f2bf(v[jj]);
      } else if constexpr (MODE == EP_SCORE) {
        unsigned short* Sg = Cb + ((size_t)blockIdx.z << 20);
        const int qt = r0 >> 6;
        const int tb = c >> 6;
        float w;
        if (tb > qt)       w = 0.0f;
        else if (tb == qt) w = 1.0f;
        else               w = exp2f((float)(qt - 1 - tb) * LOG2_09);
#pragma unroll
        for (int jj = 0; jj < 4; jj++) {
          float val = v[jj] * w;
          if (tb == qt && (c & 63) > ((r0 + jj) & 63)) val = 0.0f;  // inclusive tril in-chunk
          Sg[(size_t)(r0 + jj) * 1024 + c] = f2bf(val);
        }
      } else if constexpr (MODE == EP_PVX) {
#pragma unroll
        for (int jj = 0; jj < 4; jj++)
          Cb[((size_t)zb * SS + (size_t)zg * 1024 + r0 + jj) * DD + c] = f2bf(v[jj]);
      } else if constexpr (MODE == EP_QKV) {
        // N=3072 fused: sect 0=q (scaled, + decayed qs), 1=k (row + decayed k^T), 2=v (v^T).
        unsigned short* qb  = Cb;
        unsigned short* kb  = Ct;
        unsigned short* ktb = (unsigned short*)Cf;
        unsigned short* vtb = (unsigned short*)const_cast<float*>(resid);
        const int sect = c >> 10, cc = c & 1023;
        const int bb = r0 >> 13, s0 = r0 & (SS - 1);
        if (sect == 0) {
          const float wq_row = exp2f((float)((s0 >> 6) & 15) * LOG2_09);  // 0.9^cl
#pragma unroll
          for (int jj = 0; jj < 4; jj++) {
            qb[(size_t)(r0 + jj) * DD + cc] = f2bf(v[jj] * 0.03125f);
            Cx[(size_t)(r0 + jj) * DD + cc] = f2bf(v[jj] * 0.03125f * wq_row);
          }
        } else if (sect == 1) {
#pragma unroll
          for (int jj = 0; jj < 4; jj++)
            kb[(size_t)(r0 + jj) * DD + cc] = f2bf(v[jj]);
          const float wt = exp2f((float)(15 - ((s0 >> 6) & 15)) * LOG2_09);
          uint2 pk;
          pk.x = (unsigned)f2bf(v[0] * wt) | ((unsigned)f2bf(v[1] * wt) << 16);
          pk.y = (unsigned)f2bf(v[2] * wt) | ((unsigned)f2bf(v[3] * wt) << 16);
          *(uint2*)(ktb + ((size_t)bb * DD + cc) * SS + s0) = pk;
        } else {
          uint2 pk;
          pk.x = (unsigned)f2bf(v[0]) | ((unsigned)f2bf(v[1]) << 16);
          pk.y = (unsigned)f2bf(v[2]) | ((unsigned)f2bf(v[3]) << 16);
          *(uint2*)(vtb + ((size_t)bb * DD + cc) * SS + s0) = pk;
        }
      } else {  // EP_BF16
#pragma unroll
        for (int jj = 0; jj < 4; jj++)
          Cb[(size_t)(r0 + jj) * N + c] = f2bf(v[jj]);
      }
    }
  }
}

// ---------------- causal depthwise conv (K=4) + SiLU, gate SiLU, multiply ----------------
__global__ __launch_bounds__(256)
void convgate_kernel(const unsigned short* __restrict__ ug, const float* __restrict__ cw,
                     const float* __restrict__ cb, unsigned short* __restrict__ hin) {
  const int r = blockIdx.x;          // global row (b*S + s)
  const int c0 = threadIdx.x * 8;    // channel base [0,2048)
  const int s = r & (SS - 1);
  float acc[8];
#pragma unroll
  for (int i = 0; i < 8; i++) acc[i] = cb[c0 + i];
  for (int tap = 0; tap < 4; tap++) {
    const int ds = s - 3 + tap;
    if (ds < 0) continue;
    uint4 uv = *(const uint4*)(ug + (size_t)(r - 3 + tap) * 4096 + c0);
    float u[8]; unpack8(uv, u);
#pragma unroll
    for (int i = 0; i < 8; i++) acc[i] += u[i] * cw[tap * DI2 + c0 + i];
  }
  uint4 gv = *(const uint4*)(ug + (size_t)r * 4096 + DI2 + c0);
  float gt[8]; unpack8(gv, gt);
  unsigned short o16[8];
#pragma unroll
  for (int i = 0; i < 8; i++) {
    const float val = acc[i] / (1.0f + __expf(-acc[i]));
    const float gg  = gt[i] / (1.0f + __expf(-gt[i]));
    o16[i] = f2bf(val * gg);
  }
  uint4 ov;
  ov.x = (unsigned)o16[0] | ((unsigned)o16[1] << 16);
  ov.y = (unsigned)o16[2] | ((unsigned)o16[3] << 16);
  ov.z = (unsigned)o16[4] | ((unsigned)o16[5] << 16);
  ov.w = (unsigned)o16[6] | ((unsigned)o16[7] << 16);
  *(uint4*)(hin + (size_t)r * DI2 + c0) = ov;
}

// ---------------- superchunk prefix (in-place): Minit_g = 0.9^16 Minit_{g-1} + T_{g-1} ----------------
__global__ __launch_bounds__(256)
void prefix_kernel(unsigned short* __restrict__ Tb) {
  const int tid = blockIdx.x * 256 + threadIdx.x;  // 262144 threads
  const int b = tid >> 17, i = tid & 131071;
  unsigned short* p = Tb + (((size_t)b * 8) << 20) + (size_t)i * 8;
  float acc[8] = {};
  for (int g = 0; g < 8; g++) {
    unsigned short* pg = p + ((size_t)g << 20);
    uint4 tv = *(uint4*)pg;
    float tf_[8]; unpack8(tv, tf_);
    uint4 ov;
    ov.x = (unsigned)f2bf(acc[0]) | ((unsigned)f2bf(acc[1]) << 16);
    ov.y = (unsigned)f2bf(acc[2]) | ((unsigned)f2bf(acc[3]) << 16);
    ov.z = (unsigned)f2bf(acc[4]) | ((unsigned)f2bf(acc[5]) << 16);
    ov.w = (unsigned)f2bf(acc[6]) | ((unsigned)f2bf(acc[7]) << 16);
    *(uint4*)pg = ov;
#pragma unroll
    for (int e = 0; e < 8; e++) acc[e] = LAMBDA16 * acc[e] + tf_[e];
  }
}

extern "C" void kernel_launch(void* const* d_in, const int* in_sizes, int n_in,
                              void* d_out, int out_size, void* d_ws, size_t ws_size,
                              hipStream_t stream) {
  (void)in_sizes; (void)n_in; (void)out_size;
  const float* x      = (const float*)d_in[0];
  const float* norm_w = (const float*)d_in[1];
  const float* w_up   = (const float*)d_in[2];
  const float* w_gate = (const float*)d_in[3];
  const float* w_down = (const float*)d_in[4];
  const float* conv_w = (const float*)d_in[5];
  const float* conv_b = (const float*)d_in[6];
  const float* wq     = (const float*)d_in[7];
  const float* wk     = (const float*)d_in[8];
  const float* wv     = (const float*)d_in[9];
  const float* wo     = (const float*)d_in[10];
  float* out = (float*)d_out;

  const size_t MB = 1ull << 20;
  // Aliased workspace plan (212 MiB). Lifetimes (r14 layout):
  //   [0,32M)    ug -> hbuf -> Tbuf (after QKV gemm)
  //   [32,64M)   ug -> qbuf
  //   [64,96M)   ug -> kbuf (dead after score) -> obuf (pvx writes, final reads)
  //   [96,128M)  ug -> ktbuf (decay-scaled; dead after state) -> sbuf
  //   [128,160M) normed -> hin -> vtbuf
  //   [160,192M) hin tail (dead after down) -> qsbuf (decayed q, written by QKV)
  //   [192,212M) weight transposes (wq|wk|wv contiguous => fused [3072][1024])
  if (ws_size < 212 * MB) return;
  char* base = (char*)d_ws;
  unsigned short* ug     = (unsigned short*)(base + 0);
  unsigned short* hbuf   = (unsigned short*)(base + 0);
  unsigned short* Tbuf   = (unsigned short*)(base + 0);
  unsigned short* qbuf   = (unsigned short*)(base + 32 * MB);
  unsigned short* kbuf   = (unsigned short*)(base + 64 * MB);
  unsigned short* obuf   = (unsigned short*)(base + 64 * MB);   // overlays kbuf (dead after score)
  unsigned short* ktbuf  = (unsigned short*)(base + 96 * MB);
  unsigned short* sbuf   = (unsigned short*)(base + 96 * MB);
  unsigned short* normed = (unsigned short*)(base + 128 * MB);
  unsigned short* hin    = (unsigned short*)(base + 128 * MB);
  unsigned short* vtbuf  = (unsigned short*)(base + 128 * MB);
  unsigned short* qsbuf  = (unsigned short*)(base + 160 * MB);  // overlays hin tail (dead)
  unsigned short* wugt   = (unsigned short*)(base + 192 * MB);
  unsigned short* wdt    = (unsigned short*)(base + 200 * MB);
  unsigned short* wqkvt  = (unsigned short*)(base + 204 * MB);  // [3072][1024]: wq|wk|wv
  unsigned short* wot    = (unsigned short*)(base + 210 * MB);

  dim3 tb(32, 8);
  transpose_cast<<<dim3(DI2 / 32, DD / 32), tb, 0, stream>>>(w_up,   wugt,                    DD,  DI2);
  transpose_cast<<<dim3(DI2 / 32, DD / 32), tb, 0, stream>>>(w_gate, wugt + (size_t)DI2 * DD, DD,  DI2);
  transpose_cast<<<dim3(DD / 32, DI2 / 32), tb, 0, stream>>>(w_down, wdt, DI2, DD);
  transpose_cast<<<dim3(DD / 32, DD / 32),  tb, 0, stream>>>(wq, wqkvt,                          DD, DD);
  transpose_cast<<<dim3(DD / 32, DD / 32),  tb, 0, stream>>>(wk, wqkvt + (size_t)DD * DD,       DD, DD);
  transpose_cast<<<dim3(DD / 32, DD / 32),  tb, 0, stream>>>(wv, wqkvt + (size_t)2 * DD * DD,   DD, DD);
  transpose_cast<<<dim3(DD / 32, DD / 32),  tb, 0, stream>>>(wo, wot, DD, DD);

  rmsnorm_kernel<<<NR, 256, 0, stream>>>(x, norm_w, normed);

  // [16384,1024] @ [1024,4096] -> ug (u | gate_pre)
  gemm256<EP_BF16><<<dim3((NR / 256) * (4096 / 256)), 512, 0, stream>>>(
      normed, wugt, ug, nullptr, nullptr, nullptr, nullptr, NR, 4096, DD, DD, DD, 1.0f);

  convgate_kernel<<<NR, 256, 0, stream>>>(ug, conv_w, conv_b, hin);

  // [16384,2048] @ [2048,1024] -> h
  gemm256<EP_BF16><<<dim3((NR / 256) * (DD / 256)), 512, 0, stream>>>(
      hin, wdt, hbuf, nullptr, nullptr, nullptr, nullptr, NR, DD, DI2, DI2, DI2, 1.0f);

  // fused QKV: [16384,1024] @ [1024,3072]; epilogue: q (+decayed qs), k (+decayed k^T), v^T
  gemm256<EP_QKV><<<dim3((NR / 256) * (3072 / 256)), 512, 0, stream>>>(
      hbuf, wqkvt, qbuf, kbuf, (float*)ktbuf, (const float*)vtbuf, qsbuf,
      NR, 3072, DD, DD, DD, 1.0f);

  // Hebbian memory via superchunk decomposition (16 chunks / superchunk):
  gemm256<EP_STATE><<<dim3(16, 1, 16), 512, 0, stream>>>(
      vtbuf, ktbuf, Tbuf, nullptr, nullptr, nullptr, nullptr,
      1024, 1024, 1024, SS, SS, 1.0f);
  gemm256<EP_SCORE><<<dim3(10, 1, 16), 512, 0, stream>>>(
      qbuf, kbuf, sbuf, nullptr, nullptr, nullptr, nullptr,
      1024, 1024, 1024, DD, DD, 1.0f);
  prefix_kernel<<<1024, 256, 0, stream>>>(Tbuf);
  // O[gb] = [S_band | qs] @ [V | Minit]^T -> obuf (pv + cross fused, concatenated K)
  gemm256<EP_PVX><<<dim3(16, 1, 16), 512, 0, stream>>>(
      sbuf, vtbuf, obuf, Tbuf, nullptr, nullptr, qsbuf,
      1024, 1024, 1024, 1024, SS, 1.0f);

  // out = obuf @ wo + x
  gemm256<EP_F32_RES><<<dim3((NR / 256) * (DD / 256)), 512, 0, stream>>>(
      obuf, wot, nullptr, nullptr, out, x, nullptr, NR, DD, DD, DD, DD, 1.0f);
}

// Round 19
// 640.446 us; speedup vs baseline: 1.0831x; 1.0831x over previous
//
#include <hip/hip_runtime.h>
#include <cstdint>
#include <cstddef>

#define SS 8192
#define DD 1024
#define DI2 2048
#define NR 16384   // B*S

#define LOG2_09 (-0.152003093445050f)   // log2(0.9)
#define LAMBDA16 0.185302018885184f     // 0.9^16

typedef __attribute__((ext_vector_type(4))) float f32x4;
typedef __attribute__((ext_vector_type(8))) __bf16 bf16x8;

union U16 { uint4 u; bf16x8 b; };

static __device__ __forceinline__ f32x4 MFMA(uint4 a, uint4 b, f32x4 c) {
  U16 ua, ub; ua.u = a; ub.u = b;
  return __builtin_amdgcn_mfma_f32_16x16x32_bf16(ua.b, ub.b, c, 0, 0, 0);
}

static __device__ __forceinline__ unsigned short f2bf(float f) {
  union { float f; unsigned u; } v; v.f = f;
  return (unsigned short)((v.u + 0x7FFFu + ((v.u >> 16) & 1u)) >> 16);
}
static __device__ __forceinline__ float bf2f(unsigned b) {
  union { unsigned u; float f; } v; v.u = b << 16; return v.f;
}
static __device__ __forceinline__ void unpack8(uint4 u, float* f) {
  f[0] = bf2f(u.x & 0xFFFFu); f[1] = bf2f(u.x >> 16);
  f[2] = bf2f(u.y & 0xFFFFu); f[3] = bf2f(u.y >> 16);
  f[4] = bf2f(u.z & 0xFFFFu); f[5] = bf2f(u.z >> 16);
  f[6] = bf2f(u.w & 0xFFFFu); f[7] = bf2f(u.w >> 16);
}

// async global->LDS, 16B per lane. LDS dest is wave-uniform base + lane*16.
static __device__ __forceinline__ void glds16(const unsigned short* g, char* l) {
  __builtin_amdgcn_global_load_lds(
      (const __attribute__((address_space(1))) unsigned int*)g,
      (__attribute__((address_space(3))) unsigned int*)l, 16, 0, 0);
}

// ---------------- weight transpose + cast: out[c][r] = bf16(in[r][c]) ----------------
__global__ __launch_bounds__(256)
void transpose_cast(const float* __restrict__ in, unsigned short* __restrict__ out, int R, int Cc) {
  __shared__ float tile[32][33];
  const int r0 = blockIdx.y * 32, c0 = blockIdx.x * 32;
  const int tx = threadIdx.x, ty = threadIdx.y;
#pragma unroll
  for (int i = 0; i < 4; i++)
    tile[ty + i * 8][tx] = in[(size_t)(r0 + ty + i * 8) * Cc + c0 + tx];
  __syncthreads();
#pragma unroll
  for (int i = 0; i < 4; i++)
    out[(size_t)(c0 + ty + i * 8) * R + r0 + tx] = f2bf(tile[tx][ty + i * 8]);
}

// ---------------- RMSNorm (fp32 in -> bf16 out) ----------------
__global__ __launch_bounds__(256)
void rmsnorm_kernel(const float* __restrict__ x, const float* __restrict__ w,
                    unsigned short* __restrict__ out) {
  const int row = blockIdx.x, t = threadIdx.x;
  const float4 v = ((const float4*)(x + (size_t)row * DD))[t];
  float ss = v.x * v.x + v.y * v.y + v.z * v.z + v.w * v.w;
  __shared__ float sred[256];
  sred[t] = ss;
  __syncthreads();
  for (int o = 128; o > 0; o >>= 1) {
    if (t < o) sred[t] += sred[t + o];
    __syncthreads();
  }
  const float rr = rsqrtf(sred[0] * (1.0f / (float)DD) + 1e-5f);
  const float4 wv = ((const float4*)w)[t];
  uint2 pk;
  pk.x = (unsigned)f2bf(v.x * rr * wv.x) | ((unsigned)f2bf(v.y * rr * wv.y) << 16);
  pk.y = (unsigned)f2bf(v.z * rr * wv.z) | ((unsigned)f2bf(v.w * rr * wv.w) << 16);
  *(uint2*)(out + (size_t)row * DD + t * 4) = pk;
}

// ---------------- 256x256-tile deep-pipelined bf16 GEMM: C = A[M][.] @ Bt[N][.]^T ----------------
// 8 waves, wave grid 2Mx4N. BK=32, quad-buffered LDS (128KB), depth-3 prefetch,
// counted vmcnt(8), ONE barrier per K-tile. Empirically best of 6 schedule variants:
// 2-bar -5%, 4-bar -6%, BK=64 2-buf -11%, 8-phase -13%, depth-1 -14%.
// XCD m-slice remap when mblocks%8==0 (per-XCD A working set = 4MB = L2).
// EP_STATE/EP_SCORE: z-batched per-superchunk. EP_QKV: fused N=3072 (also writes decayed qs).
// EP_PVX: O = [S_band | qs] @ [V | Minit]^T — pv+cross merged via concatenated K.
enum { EP_BF16 = 0, EP_F32_RES = 3, EP_STATE = 4, EP_SCORE = 6, EP_PVX = 7, EP_QKV = 8 };

template <int MODE>
__global__ __launch_bounds__(512, 2)
void gemm256(const unsigned short* __restrict__ A, const unsigned short* __restrict__ Bt,
             unsigned short* __restrict__ Cb, unsigned short* __restrict__ Ct,
             float* __restrict__ Cf, const float* __restrict__ resid,
             unsigned short* __restrict__ Cx,
             int M, int N, int kLen, int lda, int ldb, float scale) {
  __shared__ char sLds[131072];
  const int t = threadIdx.x, lane = t & 63, wid = t >> 6;
  const int wr = wid >> 2, wc = wid & 3;
  const int l15 = lane & 15, lh = lane >> 4;
  const int mblocks = M >> 8;
  int m0, n0;
  if constexpr (MODE == EP_SCORE) {
    // triangular tile grid: only lower-or-diagonal 256^2 tiles (10 of 16)
    const int p = (int)blockIdx.x;
    const int mt = (p >= 6) ? 3 : (p >= 3) ? 2 : (p >= 1) ? 1 : 0;
    const int nt = p - ((mt * (mt + 1)) >> 1);
    m0 = mt << 8; n0 = nt << 8;
  } else if ((mblocks & 7) == 0) {   // XCD m-slice remap
    const int msl = mblocks >> 3;
    const int xcd = (int)blockIdx.x & 7, loc = (int)blockIdx.x >> 3;
    m0 = (xcd * msl + (loc % msl)) << 8;
    n0 = (loc / msl) << 8;
  } else {
    m0 = ((int)blockIdx.x % mblocks) << 8;
    n0 = ((int)blockIdx.x / mblocks) << 8;
  }
  int zb = 0, zg = 0;
  const unsigned short* Abase = A;
  const unsigned short* Bbase = Bt;
  if constexpr (MODE == EP_STATE || MODE == EP_SCORE || MODE == EP_PVX) {
    const int gb = blockIdx.z;
    zb = gb >> 3; zg = gb & 7;
    if constexpr (MODE == EP_STATE) {
      Abase = A + (size_t)zb * DD * SS + (size_t)zg * 1024;
      Bbase = Bt + (size_t)zb * DD * SS + (size_t)zg * 1024;
    } else if constexpr (MODE == EP_SCORE) {
      Abase = A + ((size_t)zb * SS + (size_t)zg * 1024) * (size_t)lda;
      Bbase = Bt + ((size_t)zb * SS + (size_t)zg * 1024) * (size_t)ldb;
    } else {  // EP_PVX: A = sbuf[gb], B = vt superchunk
      Abase = A + ((size_t)blockIdx.z << 20);
      Bbase = Bt + (size_t)zb * DD * SS + (size_t)zg * 1024;
    }
  }
  // staging source (inverse swizzle on the global column)
  const int srow = wid * 16 + (lane >> 2);                          // 0..127 within half
  const int scol = ((lane & 3) << 3) ^ (((srow >> 1) & 3) << 3);   // bf16 elems
  const unsigned short* pA0 = Abase + (size_t)(m0 + srow) * lda + scol;
  const unsigned short* pA1 = pA0 + (size_t)128 * lda;
  const unsigned short* pB0 = Bbase + (size_t)(n0 + srow) * ldb + scol;
  const unsigned short* pB1 = pB0 + (size_t)128 * ldb;
  const int ldsW = wid * 1024;
  int ntV = 0;
  const unsigned short *pA2 = nullptr, *pA2h = nullptr, *pB2 = nullptr, *pB2h = nullptr;
  if constexpr (MODE == EP_PVX) {
    ntV = ((m0 >> 8) + 1) << 3;  // banded S@V: k <= (mt+1)*256
    const unsigned short* qsb = Cx + ((size_t)zb * SS + (size_t)zg * 1024) * DD;
    pA2  = qsb + (size_t)(m0 + srow) * DD + scol;
    pA2h = pA2 + (size_t)128 * DD;
    const unsigned short* mnb = Ct + ((size_t)blockIdx.z << 20);
    pB2  = mnb + (size_t)(n0 + srow) * 1024 + scol;
    pB2h = pB2 + (size_t)128 * 1024;
  }
  int offA[8], offB[4];
#pragma unroll
  for (int mf = 0; mf < 8; mf++) {
    const int r = wr * 128 + mf * 16 + l15;
    offA[mf] = r * 64 + ((lh * 16) ^ (((r >> 1) & 3) << 4));
  }
#pragma unroll
  for (int nf = 0; nf < 4; nf++) {
    const int r = wc * 64 + nf * 16 + l15;
    offB[nf] = r * 64 + ((lh * 16) ^ (((r >> 1) & 3) << 4));
  }
  int NT = kLen >> 5;
  if constexpr (MODE == EP_PVX) NT = ntV + 32;  // band + Minit (K=1024)
#define BUFA(tt) (sLds + ((tt) & 3) * 32768)
#define BUFB(tt) (sLds + ((tt) & 3) * 32768 + 16384)
  auto stage = [&](int tt) {
    const int _k = tt * 32;
    const unsigned short* a0 = pA0 + _k;
    const unsigned short* a1 = pA1 + _k;
    const unsigned short* b0 = pB0 + _k;
    const unsigned short* b1 = pB1 + _k;
    if constexpr (MODE == EP_PVX) {
      if (tt >= ntV) {
        const int k2 = (tt - ntV) * 32;
        a0 = pA2 + k2; a1 = pA2h + k2;
        b0 = pB2 + k2; b1 = pB2h + k2;
      }
    }
    glds16(a0, BUFA(tt) + ldsW);
    glds16(a1, BUFA(tt) + 8192 + ldsW);
    glds16(b0, BUFB(tt) + ldsW);
    glds16(b1, BUFB(tt) + 8192 + ldsW);
  };
  stage(0); stage(1); stage(2);
  asm volatile("s_waitcnt vmcnt(8)" ::: "memory");   // tile 0 landed (own); barrier -> all waves'
  __builtin_amdgcn_s_barrier();
  f32x4 acc[8][4] = {};
  for (int kt = 0; kt < NT; ++kt) {
    const char* At  = BUFA(kt);
    const char* Bt_ = BUFB(kt);
    uint4 av[8], bv[4];
    // reads || stage (next+3) || MFMA x32: compiler interleaves by dependency
#pragma unroll
    for (int i = 0; i < 8; i++) av[i] = *(const uint4*)(At + offA[i]);
#pragma unroll
    for (int i = 0; i < 4; i++) bv[i] = *(const uint4*)(Bt_ + offB[i]);
    if (kt + 3 < NT) stage(kt + 3);  // buf (kt-1)&3: reads done pre-bar(kt-1)
    __builtin_amdgcn_s_setprio(1);
#pragma unroll
    for (int mf = 0; mf < 8; mf++)
#pragma unroll
      for (int nf = 0; nf < 4; nf++)
        acc[mf][nf] = MFMA(av[mf], bv[nf], acc[mf][nf]);
    __builtin_amdgcn_s_setprio(0);
    // counted wait for next tile, BEFORE the end barrier (all waves' DMA then landed)
    if (kt < NT - 3)       { asm volatile("s_waitcnt vmcnt(8)" ::: "memory"); }
    else if (kt == NT - 3) { asm volatile("s_waitcnt vmcnt(4)" ::: "memory"); }
    else if (kt == NT - 2) { asm volatile("s_waitcnt vmcnt(0)" ::: "memory"); }
    __builtin_amdgcn_s_barrier();
  }
#undef BUFA
#undef BUFB
#pragma unroll
  for (int mf = 0; mf < 8; mf++) {
    const int r0 = m0 + wr * 128 + mf * 16 + lh * 4;
#pragma unroll
    for (int nf = 0; nf < 4; nf++) {
      const int c = n0 + wc * 64 + nf * 16 + l15;
      f32x4 v = acc[mf][nf] * scale;
      if constexpr (MODE == EP_F32_RES) {
#pragma unroll
        for (int jj = 0; jj < 4; jj++) {
          const size_t idx = (size_t)(r0 + jj) * N + c;
          Cf[idx] = v[jj] + resid[idx];
        }
      } else if constexpr (MODE == EP_STATE) {
        unsigned short* Tg = Cb + ((size_t)blockIdx.z << 20);
#pragma unroll
        for (int jj = 0; jj < 4; jj++)
          Tg[(size_t)(r0 + jj) * 1024 + c] = f2bf(v[jj]);
      } else if constexpr (MODE == EP_SCORE) {
        unsigned short* Sg = Cb + ((size_t)blockIdx.z << 20);
        const int qt = r0 >> 6;
        const int tb = c >> 6;
        float w;
        if (tb > qt)       w = 0.0f;
        else if (tb == qt) w = 1.0f;
        else               w = exp2f((float)(qt - 1 - tb) * LOG2_09);
#pragma unroll
        for (int jj = 0; jj < 4; jj++) {
          float val = v[jj] * w;
          if (tb == qt && (c & 63) > ((r0 + jj) & 63)) val = 0.0f;  // inclusive tril in-chunk
          Sg[(size_t)(r0 + jj) * 1024 + c] = f2bf(val);
        }
      } else if constexpr (MODE == EP_PVX) {
#pragma unroll
        for (int jj = 0; jj < 4; jj++)
          Cb[((size_t)zb * SS + (size_t)zg * 1024 + r0 + jj) * DD + c] = f2bf(v[jj]);
      } else if constexpr (MODE == EP_QKV) {
        // N=3072 fused: sect 0=q (scaled, + decayed qs), 1=k (row + decayed k^T), 2=v (v^T).
        unsigned short* qb  = Cb;
        unsigned short* kb  = Ct;
        unsigned short* ktb = (unsigned short*)Cf;
        unsigned short* vtb = (unsigned short*)const_cast<float*>(resid);
        const int sect = c >> 10, cc = c & 1023;
        const int bb = r0 >> 13, s0 = r0 & (SS - 1);
        if (sect == 0) {
          const float wq_row = exp2f((float)((s0 >> 6) & 15) * LOG2_09);  // 0.9^cl
#pragma unroll
          for (int jj = 0; jj < 4; jj++) {
            qb[(size_t)(r0 + jj) * DD + cc] = f2bf(v[jj] * 0.03125f);
            Cx[(size_t)(r0 + jj) * DD + cc] = f2bf(v[jj] * 0.03125f * wq_row);
          }
        } else if (sect == 1) {
#pragma unroll
          for (int jj = 0; jj < 4; jj++)
            kb[(size_t)(r0 + jj) * DD + cc] = f2bf(v[jj]);
          const float wt = exp2f((float)(15 - ((s0 >> 6) & 15)) * LOG2_09);
          uint2 pk;
          pk.x = (unsigned)f2bf(v[0] * wt) | ((unsigned)f2bf(v[1] * wt) << 16);
          pk.y = (unsigned)f2bf(v[2] * wt) | ((unsigned)f2bf(v[3] * wt) << 16);
          *(uint2*)(ktb + ((size_t)bb * DD + cc) * SS + s0) = pk;
        } else {
          uint2 pk;
          pk.x = (unsigned)f2bf(v[0]) | ((unsigned)f2bf(v[1]) << 16);
          pk.y = (unsigned)f2bf(v[2]) | ((unsigned)f2bf(v[3]) << 16);
          *(uint2*)(vtb + ((size_t)bb * DD + cc) * SS + s0) = pk;
        }
      } else {  // EP_BF16
#pragma unroll
        for (int jj = 0; jj < 4; jj++)
          Cb[(size_t)(r0 + jj) * N + c] = f2bf(v[jj]);
      }
    }
  }
}

// ---------------- causal depthwise conv (K=4) + SiLU, gate SiLU, multiply ----------------
__global__ __launch_bounds__(256)
void convgate_kernel(const unsigned short* __restrict__ ug, const float* __restrict__ cw,
                     const float* __restrict__ cb, unsigned short* __restrict__ hin) {
  const int r = blockIdx.x;          // global row (b*S + s)
  const int c0 = threadIdx.x * 8;    // channel base [0,2048)
  const int s = r & (SS - 1);
  float acc[8];
#pragma unroll
  for (int i = 0; i < 8; i++) acc[i] = cb[c0 + i];
  for (int tap = 0; tap < 4; tap++) {
    const int ds = s - 3 + tap;
    if (ds < 0) continue;
    uint4 uv = *(const uint4*)(ug + (size_t)(r - 3 + tap) * 4096 + c0);
    float u[8]; unpack8(uv, u);
#pragma unroll
    for (int i = 0; i < 8; i++) acc[i] += u[i] * cw[tap * DI2 + c0 + i];
  }
  uint4 gv = *(const uint4*)(ug + (size_t)r * 4096 + DI2 + c0);
  float gt[8]; unpack8(gv, gt);
  unsigned short o16[8];
#pragma unroll
  for (int i = 0; i < 8; i++) {
    const float val = acc[i] / (1.0f + __expf(-acc[i]));
    const float gg  = gt[i] / (1.0f + __expf(-gt[i]));
    o16[i] = f2bf(val * gg);
  }
  uint4 ov;
  ov.x = (unsigned)o16[0] | ((unsigned)o16[1] << 16);
  ov.y = (unsigned)o16[2] | ((unsigned)o16[3] << 16);
  ov.z = (unsigned)o16[4] | ((unsigned)o16[5] << 16);
  ov.w = (unsigned)o16[6] | ((unsigned)o16[7] << 16);
  *(uint4*)(hin + (size_t)r * DI2 + c0) = ov;
}

// ---------------- superchunk prefix (in-place): Minit_g = 0.9^16 Minit_{g-1} + T_{g-1} ----------------
__global__ __launch_bounds__(256)
void prefix_kernel(unsigned short* __restrict__ Tb) {
  const int tid = blockIdx.x * 256 + threadIdx.x;  // 262144 threads
  const int b = tid >> 17, i = tid & 131071;
  unsigned short* p = Tb + (((size_t)b * 8) << 20) + (size_t)i * 8;
  float acc[8] = {};
  for (int g = 0; g < 8; g++) {
    unsigned short* pg = p + ((size_t)g << 20);
    uint4 tv = *(uint4*)pg;
    float tf_[8]; unpack8(tv, tf_);
    uint4 ov;
    ov.x = (unsigned)f2bf(acc[0]) | ((unsigned)f2bf(acc[1]) << 16);
    ov.y = (unsigned)f2bf(acc[2]) | ((unsigned)f2bf(acc[3]) << 16);
    ov.z = (unsigned)f2bf(acc[4]) | ((unsigned)f2bf(acc[5]) << 16);
    ov.w = (unsigned)f2bf(acc[6]) | ((unsigned)f2bf(acc[7]) << 16);
    *(uint4*)pg = ov;
#pragma unroll
    for (int e = 0; e < 8; e++) acc[e] = LAMBDA16 * acc[e] + tf_[e];
  }
}

extern "C" void kernel_launch(void* const* d_in, const int* in_sizes, int n_in,
                              void* d_out, int out_size, void* d_ws, size_t ws_size,
                              hipStream_t stream) {
  (void)in_sizes; (void)n_in; (void)out_size;
  const float* x      = (const float*)d_in[0];
  const float* norm_w = (const float*)d_in[1];
  const float* w_up   = (const float*)d_in[2];
  const float* w_gate = (const float*)d_in[3];
  const float* w_down = (const float*)d_in[4];
  const float* conv_w = (const float*)d_in[5];
  const float* conv_b = (const float*)d_in[6];
  const float* wq     = (const float*)d_in[7];
  const float* wk     = (const float*)d_in[8];
  const float* wv     = (const float*)d_in[9];
  const float* wo     = (const float*)d_in[10];
  float* out = (float*)d_out;

  const size_t MB = 1ull << 20;
  // Aliased workspace plan (212 MiB). Lifetimes:
  //   [0,32M)    ug -> hbuf -> Tbuf (after QKV gemm)
  //   [32,64M)   ug -> qbuf
  //   [64,96M)   ug -> kbuf (dead after score) -> obuf (pvx writes, final reads)
  //   [96,128M)  ug -> ktbuf (decay-scaled; dead after state) -> sbuf
  //   [128,160M) normed -> hin -> vtbuf
  //   [160,192M) hin tail (dead after down) -> qsbuf (decayed q, written by QKV)
  //   [192,212M) weight transposes (wq|wk|wv contiguous => fused [3072][1024])
  if (ws_size < 212 * MB) return;
  char* base = (char*)d_ws;
  unsigned short* ug     = (unsigned short*)(base + 0);
  unsigned short* hbuf   = (unsigned short*)(base + 0);
  unsigned short* Tbuf   = (unsigned short*)(base + 0);
  unsigned short* qbuf   = (unsigned short*)(base + 32 * MB);
  unsigned short* kbuf   = (unsigned short*)(base + 64 * MB);
  unsigned short* obuf   = (unsigned short*)(base + 64 * MB);   // overlays kbuf (dead after score)
  unsigned short* ktbuf  = (unsigned short*)(base + 96 * MB);
  unsigned short* sbuf   = (unsigned short*)(base + 96 * MB);
  unsigned short* normed = (unsigned short*)(base + 128 * MB);
  unsigned short* hin    = (unsigned short*)(base + 128 * MB);
  unsigned short* vtbuf  = (unsigned short*)(base + 128 * MB);
  unsigned short* qsbuf  = (unsigned short*)(base + 160 * MB);  // overlays hin tail (dead)
  unsigned short* wugt   = (unsigned short*)(base + 192 * MB);
  unsigned short* wdt    = (unsigned short*)(base + 200 * MB);
  unsigned short* wqkvt  = (unsigned short*)(base + 204 * MB);  // [3072][1024]: wq|wk|wv
  unsigned short* wot    = (unsigned short*)(base + 210 * MB);

  dim3 tb(32, 8);
  transpose_cast<<<dim3(DI2 / 32, DD / 32), tb, 0, stream>>>(w_up,   wugt,                    DD,  DI2);
  transpose_cast<<<dim3(DI2 / 32, DD / 32), tb, 0, stream>>>(w_gate, wugt + (size_t)DI2 * DD, DD,  DI2);
  transpose_cast<<<dim3(DD / 32, DI2 / 32), tb, 0, stream>>>(w_down, wdt, DI2, DD);
  transpose_cast<<<dim3(DD / 32, DD / 32),  tb, 0, stream>>>(wq, wqkvt,                          DD, DD);
  transpose_cast<<<dim3(DD / 32, DD / 32),  tb, 0, stream>>>(wk, wqkvt + (size_t)DD * DD,       DD, DD);
  transpose_cast<<<dim3(DD / 32, DD / 32),  tb, 0, stream>>>(wv, wqkvt + (size_t)2 * DD * DD,   DD, DD);
  transpose_cast<<<dim3(DD / 32, DD / 32),  tb, 0, stream>>>(wo, wot, DD, DD);

  rmsnorm_kernel<<<NR, 256, 0, stream>>>(x, norm_w, normed);

  // [16384,1024] @ [1024,4096] -> ug (u | gate_pre); grid 64*16 = 1024 blocks
  gemm256<EP_BF16><<<dim3((NR / 256) * (4096 / 256)), 512, 0, stream>>>(
      normed, wugt, ug, nullptr, nullptr, nullptr, nullptr, NR, 4096, DD, DD, DD, 1.0f);

  convgate_kernel<<<NR, 256, 0, stream>>>(ug, conv_w, conv_b, hin);

  // [16384,2048] @ [2048,1024] -> h; grid 64*4 = 256
  gemm256<EP_BF16><<<dim3((NR / 256) * (DD / 256)), 512, 0, stream>>>(
      hin, wdt, hbuf, nullptr, nullptr, nullptr, nullptr, NR, DD, DI2, DI2, DI2, 1.0f);

  // fused QKV: [16384,1024] @ [1024,3072]; epilogue: q (+decayed qs), k (+decayed k^T), v^T
  gemm256<EP_QKV><<<dim3((NR / 256) * (3072 / 256)), 512, 0, stream>>>(
      hbuf, wqkvt, qbuf, kbuf, (float*)ktbuf, (const float*)vtbuf, qsbuf,
      NR, 3072, DD, DD, DD, 1.0f);

  // Hebbian memory via superchunk decomposition (16 chunks / superchunk):
  // T[gb] = (V^T) @ (decayed K)-slice  — ktbuf already carries the decay weights.
  gemm256<EP_STATE><<<dim3(16, 1, 16), 512, 0, stream>>>(
      vtbuf, ktbuf, Tbuf, nullptr, nullptr, nullptr, nullptr,
      1024, 1024, 1024, SS, SS, 1.0f);
  // S[gb] = decay/tril-weighted Q K^T (lower-triangular 256^2 tiles only) -> sbuf
  gemm256<EP_SCORE><<<dim3(10, 1, 16), 512, 0, stream>>>(
      qbuf, kbuf, sbuf, nullptr, nullptr, nullptr, nullptr,
      1024, 1024, 1024, DD, DD, 1.0f);
  prefix_kernel<<<1024, 256, 0, stream>>>(Tbuf);
  // O[gb] = [S_band | qs] @ [V | Minit]^T -> obuf (pv + cross fused, concatenated K)
  gemm256<EP_PVX><<<dim3(16, 1, 16), 512, 0, stream>>>(
      sbuf, vtbuf, obuf, Tbuf, nullptr, nullptr, qsbuf,
      1024, 1024, 1024, 1024, SS, 1.0f);

  // out = obuf @ wo + x; grid 256
  gemm256<EP_F32_RES><<<dim3((NR / 256) * (DD / 256)), 512, 0, stream>>>(
      obuf, wot, nullptr, nullptr, out, x, nullptr, NR, DD, DD, DD, DD, 1.0f);
}